// Round 1
// 1351.178 us; speedup vs baseline: 1.0935x; 1.0935x over previous
//
#include <hip/hip_runtime.h>
#include <math.h>

// Problem constants (fixed by setup_inputs).
#define TT 16384
#define HH 4096
#define EE 256

typedef _Float16 f16x8 __attribute__((ext_vector_type(8)));
typedef float f32x4 __attribute__((ext_vector_type(4)));

// ---------------------------------------------------------------------------
// CAS-based double atomic add (no dependence on -munsafe-fp-atomics).
__device__ inline void atom_add_double(double* addr, double val) {
    unsigned long long* p = (unsigned long long*)addr;
    unsigned long long old = *p, assumed;
    do {
        assumed = old;
        double nv = __longlong_as_double(assumed) + val;
        old = atomicCAS(p, assumed, __double_as_longlong(nv));
    } while (old != assumed);
}

__global__ __launch_bounds__(64) void zero_ws_kernel(double* z) {
    if (threadIdx.x == 0) *z = 0.0;
}

__global__ __launch_bounds__(64) void finalize_z_kernel(const double* zacc,
                                                        float* zout) {
    if (threadIdx.x == 0)
        *zout = (float)(*zacc / (double)((size_t)TT * (size_t)EE));
}

// ---------------------------------------------------------------------------
// Prep: W (E x H fp32) -> fp16 planes: hi = f16(w), lo = f16((w - hi)*2048).
// Layout: wpl[0][e][k] = hi, wpl[1][e][k] = lo (each E*H f16, row-major).
// Also zeroes the z-loss accumulator.
__global__ __launch_bounds__(256) void prep_w_kernel(
    const float* __restrict__ w, _Float16* __restrict__ wpl,
    double* __restrict__ zacc)
{
    if (blockIdx.x == 0 && threadIdx.x == 0) *zacc = 0.0;
    const int e = blockIdx.x;
    for (int c = threadIdx.x; c < 512; c += 256) {   // 512 chunks of 8 per row
        const int k = c << 3;
        const float* src = w + (size_t)e * HH + k;
        const float4 f0 = *(const float4*)src;
        const float4 f1 = *(const float4*)(src + 4);
        const float fs[8] = {f0.x, f0.y, f0.z, f0.w, f1.x, f1.y, f1.z, f1.w};
        f16x8 hi, lo;
#pragma unroll
        for (int q = 0; q < 8; ++q) {
            _Float16 h = (_Float16)fs[q];
            hi[q] = h;
            lo[q] = (_Float16)((fs[q] - (float)h) * 2048.0f);
        }
        *(f16x8*)(wpl + (size_t)e * HH + k) = hi;
        *(f16x8*)(wpl + (size_t)EE * HH + (size_t)e * HH + k) = lo;
    }
}

// ---------------------------------------------------------------------------
// MFMA GEMM: raw = x @ W^T via fp16 two-term split, 3 products:
//   raw = sum(xh*wh)  +  [sum(xh*wl') + sum(xl'*wh)] / 2048     (ll dropped)
// Tile: BM=64 x BN=128, BK=32. 256 threads = 4 waves (2M x 2N), wave-tile
// 32x64 (M_rep=2, N_rep=4 frags of 16x16). Double-buffered LDS, XOR
// chunk-swizzle (c ^= (row>>1)&3) -> conflict-free ds_read_b128/write_b128.
// Grid 512 = 2 blocks/CU = 2 waves/SIMD. XCD swizzle keeps both N-halves of
// a row band on one XCD (x slab L2 reuse).
__global__ __launch_bounds__(256, 2) void gemm_mfma_kernel(
    const float* __restrict__ x,        // (TT, HH) fp32
    const _Float16* __restrict__ wpl,   // [2][EE][HH] f16 planes
    float* __restrict__ logits,         // (TT, EE)
    double* __restrict__ zacc)
{
    // Per-buffer: A planes 2*64*32*2B = 8 KiB, B planes 2*128*32*2B = 16 KiB.
    __shared__ __align__(16) unsigned char sm[2][24576];

    const int tid = threadIdx.x;
    const int b = blockIdx.x;
    const int swz = ((b & 7) << 6) + (b >> 3);   // XCD-aware remap (512 = 8*64)
    const int bm = swz >> 1, bn = swz & 1;
    const int row0 = bm << 6;                    // *64
    const int col0 = bn << 7;                    // *128

    // --- staging decomposition ---
    // A: thread -> (row ar, chunk ac) of the 64x32 fp32 slab (8 floats).
    const int ar = tid >> 2;
    const int ac = tid & 3;
    const float* aSrc = x + (size_t)(row0 + ar) * HH + (ac << 3);
    const int aDstHi = (ar << 6) + ((ac ^ ((ar >> 1) & 3)) << 4);
    const int aDstLo = 4096 + aDstHi;
    // B: 4 jobs/thread over [p][128 rows][4 chunks] (16 B each).
    const _Float16* bSrc[4];
    int bDst[4];
#pragma unroll
    for (int q = 0; q < 4; ++q) {
        const int jj = tid + (q << 8);
        const int p = jj >> 9, rem = jj & 511, r = rem >> 2, c = rem & 3;
        bSrc[q] = wpl + (size_t)p * ((size_t)EE * HH) +
                  (size_t)(col0 + r) * HH + (c << 3);
        bDst[q] = 8192 + (p << 13) + (r << 6) + ((c ^ ((r >> 1) & 3)) << 4);
    }

    // --- fragment read offsets ---
    const int lane = tid & 63;
    const int wid = tid >> 6;
    const int wm = wid >> 1, wn = wid & 1;
    const int lr = lane & 15, lc = lane >> 4;
    int aOff[2][2], bOff[4][2];
#pragma unroll
    for (int i = 0; i < 2; ++i) {
        const int r = (wm << 5) + (i << 4) + lr;
        const int base = (r << 6) + ((lc ^ ((r >> 1) & 3)) << 4);
        aOff[i][0] = base;
        aOff[i][1] = base + 4096;
    }
#pragma unroll
    for (int j = 0; j < 4; ++j) {
        const int r = (wn << 6) + (j << 4) + lr;
        const int base = 8192 + (r << 6) + ((lc ^ ((r >> 1) & 3)) << 4);
        bOff[j][0] = base;
        bOff[j][1] = base + 8192;
    }

    f32x4 accP[2][4] = {};
    f32x4 accS[2][4] = {};
    float4 fa0, fa1;
    uint4 bq0, bq1, bq2, bq3;

#define LOADG(T)                                                              \
    {                                                                         \
        const float* ap = aSrc + (size_t)(T) * 32;                            \
        fa0 = *(const float4*)ap;                                             \
        fa1 = *(const float4*)(ap + 4);                                       \
        bq0 = *(const uint4*)(bSrc[0] + (size_t)(T) * 32);                    \
        bq1 = *(const uint4*)(bSrc[1] + (size_t)(T) * 32);                    \
        bq2 = *(const uint4*)(bSrc[2] + (size_t)(T) * 32);                    \
        bq3 = *(const uint4*)(bSrc[3] + (size_t)(T) * 32);                    \
    }

#define CVTWR(BUF)                                                            \
    {                                                                         \
        const float fs[8] = {fa0.x, fa0.y, fa0.z, fa0.w,                      \
                             fa1.x, fa1.y, fa1.z, fa1.w};                     \
        f16x8 hi, lo;                                                         \
        _Pragma("unroll") for (int e8 = 0; e8 < 8; ++e8)                      \
        {                                                                     \
            _Float16 h = (_Float16)fs[e8];                                    \
            hi[e8] = h;                                                       \
            lo[e8] = (_Float16)((fs[e8] - (float)h) * 2048.0f);               \
        }                                                                     \
        *(f16x8*)(&sm[BUF][aDstHi]) = hi;                                     \
        *(f16x8*)(&sm[BUF][aDstLo]) = lo;                                     \
        *(uint4*)(&sm[BUF][bDst[0]]) = bq0;                                   \
        *(uint4*)(&sm[BUF][bDst[1]]) = bq1;                                   \
        *(uint4*)(&sm[BUF][bDst[2]]) = bq2;                                   \
        *(uint4*)(&sm[BUF][bDst[3]]) = bq3;                                   \
    }

    LOADG(0);
    CVTWR(0);

#pragma unroll 2
    for (int t = 0; t < 128; ++t) {
        __syncthreads();
        const int cur = t & 1;
        if (t < 127) LOADG(t + 1);

        f16x8 ah[2][2], bh[4][2];
#pragma unroll
        for (int i = 0; i < 2; ++i) {
            ah[i][0] = *(const f16x8*)(&sm[cur][aOff[i][0]]);
            ah[i][1] = *(const f16x8*)(&sm[cur][aOff[i][1]]);
        }
#pragma unroll
        for (int j = 0; j < 4; ++j) {
            bh[j][0] = *(const f16x8*)(&sm[cur][bOff[j][0]]);
            bh[j][1] = *(const f16x8*)(&sm[cur][bOff[j][1]]);
        }
#pragma unroll
        for (int i = 0; i < 2; ++i)
#pragma unroll
            for (int j = 0; j < 4; ++j) {
                accP[i][j] = __builtin_amdgcn_mfma_f32_16x16x32_f16(
                    ah[i][0], bh[j][0], accP[i][j], 0, 0, 0);
                accS[i][j] = __builtin_amdgcn_mfma_f32_16x16x32_f16(
                    ah[i][0], bh[j][1], accS[i][j], 0, 0, 0);
                accS[i][j] = __builtin_amdgcn_mfma_f32_16x16x32_f16(
                    ah[i][1], bh[j][0], accS[i][j], 0, 0, 0);
            }

        if (t < 127) CVTWR(1 - cur);
    }
#undef LOADG
#undef CVTWR

    // Epilogue: recombine scales, z-loss partial, sigmoid, store logits.
    // C/D layout: col = lane&15, row = (lane>>4)*4 + reg  [m89-verified].
    float zs = 0.f;
#pragma unroll
    for (int i = 0; i < 2; ++i)
#pragma unroll
        for (int j = 0; j < 4; ++j) {
            const int rbase = row0 + (wm << 5) + (i << 4) + (lc << 2);
            const int col = col0 + (wn << 6) + (j << 4) + lr;
#pragma unroll
            for (int r = 0; r < 4; ++r) {
                const float raw =
                    accP[i][j][r] + accS[i][j][r] * 4.8828125e-4f;
                zs = fmaf(raw, raw, zs);
                logits[(size_t)(rbase + r) * EE + col] =
                    1.f / (1.f + expf(-raw));
            }
        }
#pragma unroll
    for (int d = 32; d; d >>= 1) zs += __shfl_xor(zs, d);
    __shared__ float zred[4];
    if (lane == 0) zred[wid] = zs;
    __syncthreads();
    if (tid == 0)
        atom_add_double(zacc, (double)(zred[0] + zred[1] + zred[2] + zred[3]));
}

// ---------------------------------------------------------------------------
// Fallback fp32 GEMM (previous session's verified kernel) for tiny workspaces.
#define BM 32
#define BK 32
__global__ __launch_bounds__(256) void gemm_fp32_fb_kernel(
    const float* __restrict__ x, const float* __restrict__ w,
    float* __restrict__ logits, double* __restrict__ zacc)
{
    __shared__ float As[BM][BK + 1];
    __shared__ float Bs[EE][BK + 1];
    __shared__ float zred[256];

    const int tid = threadIdx.x;
    const int row0 = blockIdx.x * BM;
    const int ty = tid >> 5;
    const int tx = tid & 31;
    const int lrow = tid >> 3;
    const int lk = (tid & 7) << 2;

    float acc[4][8];
#pragma unroll
    for (int i = 0; i < 4; ++i)
#pragma unroll
        for (int j = 0; j < 8; ++j) acc[i][j] = 0.f;

    for (int k0 = 0; k0 < HH; k0 += BK) {
        float4 xa = *(const float4*)(x + (size_t)(row0 + lrow) * HH + k0 + lk);
        As[lrow][lk + 0] = xa.x;
        As[lrow][lk + 1] = xa.y;
        As[lrow][lk + 2] = xa.z;
        As[lrow][lk + 3] = xa.w;
#pragma unroll
        for (int j = 0; j < 8; ++j) {
            const int e = lrow + (j << 5);
            float4 wb = *(const float4*)(w + (size_t)e * HH + k0 + lk);
            Bs[e][lk + 0] = wb.x;
            Bs[e][lk + 1] = wb.y;
            Bs[e][lk + 2] = wb.z;
            Bs[e][lk + 3] = wb.w;
        }
        __syncthreads();
#pragma unroll 8
        for (int kk = 0; kk < BK; ++kk) {
            float a[4], bb[8];
#pragma unroll
            for (int i = 0; i < 4; ++i) a[i] = As[ty * 4 + i][kk];
#pragma unroll
            for (int j = 0; j < 8; ++j) bb[j] = Bs[tx + (j << 5)][kk];
#pragma unroll
            for (int i = 0; i < 4; ++i)
#pragma unroll
                for (int j = 0; j < 8; ++j)
                    acc[i][j] = fmaf(a[i], bb[j], acc[i][j]);
        }
        __syncthreads();
    }

    float zs = 0.f;
#pragma unroll
    for (int i = 0; i < 4; ++i) {
        const int r = row0 + ty * 4 + i;
#pragma unroll
        for (int j = 0; j < 8; ++j) {
            const float v = acc[i][j];
            zs = fmaf(v, v, zs);
            logits[(size_t)r * EE + tx + (j << 5)] = 1.f / (1.f + expf(-v));
        }
    }
    zred[tid] = zs;
    __syncthreads();
    for (int s = 128; s > 0; s >>= 1) {
        if (tid < s) zred[tid] += zred[tid + s];
        __syncthreads();
    }
    if (tid == 0) atom_add_double(zacc, (double)zred[0]);
}

// ---------------------------------------------------------------------------
// Router: one wave (64 lanes) per token; lane l owns experts 4l..4l+3.
// Matches jax.lax.top_k stability: ties broken toward the LOWER index.
__global__ __launch_bounds__(256) void router_kernel(
    const float* __restrict__ logits, const float* __restrict__ bias,
    float* __restrict__ wout, float* __restrict__ iout)
{
    const int lane = threadIdx.x & 63;
    const int wv = threadIdx.x >> 6;
    const int t = blockIdx.x * 4 + wv;

    const float* lrow = logits + (size_t)t * EE + lane * 4;
    float lg[4];
#pragma unroll
    for (int q = 0; q < 4; ++q) lg[q] = lrow[q];
    const float4 b4 = *(const float4*)(bias + lane * 4);
    const float bb[4] = {b4.x, b4.y, b4.z, b4.w};

    float sel[4];
#pragma unroll
    for (int q = 0; q < 4; ++q) sel[q] = lg[q] + bb[q];

    float m1 = sel[0], m2 = -INFINITY;
#pragma unroll
    for (int q = 1; q < 4; ++q) {
        if (sel[q] > m1) { m2 = m1; m1 = sel[q]; }
        else             { m2 = fmaxf(m2, sel[q]); }
    }
#pragma unroll
    for (int d = 1; d < 8; d <<= 1) {
        const float o1 = __shfl_xor(m1, d);
        const float o2 = __shfl_xor(m2, d);
        const float nm1 = fmaxf(m1, o1);
        const float nm2 = fmaxf(fminf(m1, o1), fmaxf(m2, o2));
        m1 = nm1; m2 = nm2;
    }
    const float gs = m1 + m2;
    const int g = lane >> 3;

    int rank = 0;
#pragma unroll
    for (int gp = 0; gp < 8; ++gp) {
        const float og = __shfl(gs, gp << 3);
        rank += (og > gs) || (og == gs && gp < g);
    }
    const bool keep = rank < 4;

    float ms[4];
#pragma unroll
    for (int q = 0; q < 4; ++q)
        ms[q] = keep ? sel[q] : -3.402823466e38f;

    float wvals[8];
    int widx[8];
#pragma unroll
    for (int it = 0; it < 8; ++it) {
        float bv = ms[0];
        int bq = 0;
#pragma unroll
        for (int q = 1; q < 4; ++q)
            if (ms[q] > bv) { bv = ms[q]; bq = q; }
        int bi = (lane << 2) + bq;
        float bl = lg[bq];
#pragma unroll
        for (int d = 1; d < 64; d <<= 1) {
            const float ov = __shfl_xor(bv, d);
            const int oi = __shfl_xor(bi, d);
            const float ol = __shfl_xor(bl, d);
            if (ov > bv || (ov == bv && oi < bi)) { bv = ov; bi = oi; bl = ol; }
        }
        wvals[it] = bl;
        widx[it] = bi;
        if ((bi >> 2) == lane) ms[bi & 3] = -INFINITY;
    }

    float s = 0.f;
#pragma unroll
    for (int it = 0; it < 8; ++it) s += wvals[it];
    s = fmaxf(s, 1e-9f);

    if (lane == 0) {
#pragma unroll
        for (int it = 0; it < 8; ++it) {
            wout[(size_t)t * 8 + it] = wvals[it] / s;
            iout[(size_t)t * 8 + it] = (float)widx[it];
        }
    }
}

// ---------------------------------------------------------------------------
extern "C" void kernel_launch(void* const* d_in, const int* in_sizes, int n_in,
                              void* d_out, int out_size, void* d_ws,
                              size_t ws_size, hipStream_t stream) {
    const float* x = (const float*)d_in[0];     // (TT, HH)
    const float* w = (const float*)d_in[1];     // (EE, HH)
    const float* bias = (const float*)d_in[2];  // (EE)

    float* out = (float*)d_out;
    float* wout = out;
    float* iout = out + (size_t)TT * 8;
    float* zout = out + (size_t)TT * 16;
    float* logits = zout + 1;
    double* zacc = (double*)d_ws;

    const size_t need = 256 + (size_t)2 * EE * HH * sizeof(_Float16);
    if (ws_size >= need) {
        _Float16* wpl = (_Float16*)((char*)d_ws + 256);
        prep_w_kernel<<<EE, 256, 0, stream>>>(w, wpl, zacc);
        gemm_mfma_kernel<<<(TT / 64) * 2, 256, 0, stream>>>(x, wpl, logits,
                                                            zacc);
    } else {
        zero_ws_kernel<<<1, 64, 0, stream>>>(zacc);
        gemm_fp32_fb_kernel<<<TT / BM, 256, 0, stream>>>(x, w, logits, zacc);
    }
    finalize_z_kernel<<<1, 64, 0, stream>>>(zacc, zout);
    router_kernel<<<TT / 4, 256, 0, stream>>>(logits, bias, wout, iout);
}

// Round 4
// 551.599 us; speedup vs baseline: 2.6786x; 2.4496x over previous
//
#include <hip/hip_runtime.h>
#include <math.h>

// Problem constants (fixed by setup_inputs).
#define TT 16384
#define HH 4096
#define EE 256

typedef _Float16 f16x8 __attribute__((ext_vector_type(8)));
typedef float f32x4 __attribute__((ext_vector_type(4)));

// ---------------------------------------------------------------------------
// CAS-based double atomic add (fallback path only).
__device__ inline void atom_add_double(double* addr, double val) {
    unsigned long long* p = (unsigned long long*)addr;
    unsigned long long old = *p, assumed;
    do {
        assumed = old;
        double nv = __longlong_as_double(assumed) + val;
        old = atomicCAS(p, assumed, __double_as_longlong(nv));
    } while (old != assumed);
}

__global__ __launch_bounds__(64) void zero_ws_kernel(double* z) {
    if (threadIdx.x == 0) *z = 0.0;
}

__global__ __launch_bounds__(64) void finalize_z_kernel(const double* zacc,
                                                        float* zout) {
    if (threadIdx.x == 0)
        *zout = (float)(*zacc / (double)((size_t)TT * (size_t)EE));
}

__global__ __launch_bounds__(256) void finalize_zpart_kernel(
    const double* __restrict__ zpart, float* __restrict__ zout) {
    __shared__ double zr[256];
    zr[threadIdx.x] = zpart[threadIdx.x];
    __syncthreads();
    for (int s = 128; s > 0; s >>= 1) {
        if (threadIdx.x < s) zr[threadIdx.x] += zr[threadIdx.x + s];
        __syncthreads();
    }
    if (threadIdx.x == 0)
        *zout = (float)(zr[0] / ((double)TT * (double)EE));
}

// ---------------------------------------------------------------------------
// Prep: W (E x H fp32) -> f16 planes: hi = f16(w), lo = f16((w - hi)*2048).
__global__ __launch_bounds__(256) void prep_w_kernel(
    const float* __restrict__ w, _Float16* __restrict__ wpl)
{
    const int e = blockIdx.x;
    for (int c = threadIdx.x; c < 512; c += 256) {
        const int k = c << 3;
        const float* src = w + (size_t)e * HH + k;
        const float4 f0 = *(const float4*)src;
        const float4 f1 = *(const float4*)(src + 4);
        const float fs[8] = {f0.x, f0.y, f0.z, f0.w, f1.x, f1.y, f1.z, f1.w};
        f16x8 hi, lo;
#pragma unroll
        for (int q = 0; q < 8; ++q) {
            _Float16 h = (_Float16)fs[q];
            hi[q] = h;
            lo[q] = (_Float16)((fs[q] - (float)h) * 2048.0f);
        }
        *(f16x8*)(wpl + (size_t)e * HH + k) = hi;
        *(f16x8*)(wpl + (size_t)EE * HH + (size_t)e * HH + k) = lo;
    }
}

// ---------------------------------------------------------------------------
// MFMA GEMM v3: raw = x @ W^T via fp16 two-term split:
//   raw = sum(xh*wh) + [sum(xh*wl') + sum(xl'*wh)] / 2048      (ll dropped)
// Tile BM=64 x BN=256 (full E), BK=32. 512 threads = 8 waves (2M x 4N),
// wave-tile 32x64 (M_rep=2, N_rep=4). Grid 256 = 1 block/CU; x read once.
// Reg-staged (R1-proven mechanics) + RAW barriers (lgkmcnt(0)+s_barrier, no
// vmcnt drain) so global loads pipeline across K-steps: x prefetched 2 deep,
// W-hi 1 deep. W-lo plane skips LDS: wave-private fragments loaded per-lane
// from L2 (wpl is 4MB = L2-resident), ping-ponged registers, 1 step ahead.
// LDS per buffer 24576 B: A-hi @0 (4K), A-lo @4096 (4K), B-hi @8192 (16K).
// XOR slot swizzle (c ^ (r>>1)&3) on all staged tiles -> 2-way (free) LDS.
__global__ __launch_bounds__(512, 2) void gemm_mfma_kernel(
    const float* __restrict__ x,        // (TT, HH) fp32
    const _Float16* __restrict__ wpl,   // [2][EE][HH] f16 planes
    float* __restrict__ logits,         // (TT, EE)
    double* __restrict__ zpart)         // (256) per-block z partials
{
    __shared__ __align__(16) unsigned char sm[2][24576];
    __shared__ float zred[8];

    const int tid  = threadIdx.x;
    const int lane = tid & 63;
    const int wid  = tid >> 6;          // 0..7
    const int wm   = wid >> 2;          // 0..1 (row half)
    const int wn   = wid & 3;           // 0..3 (col quarter)
    const int lr   = lane & 15;
    const int lc   = lane >> 4;
    const int row0 = blockIdx.x << 6;

    // ---- A staging (threads 0..255): 32 B of x (8 fp32) per thread/step.
    const int arow = tid >> 2, ac32 = tid & 3;
    const float* aSrc = x + (size_t)(row0 + arow) * HH + (ac32 << 3);
    const int aDst = (arow << 6) + ((ac32 ^ ((arow >> 1) & 3)) << 4);

    // ---- B-hi staging: 2 x 16 B jobs per thread/step (rows br, br+128).
    const int br = tid >> 2, bc4 = tid & 3;
    const _Float16* bhiSrc = wpl + (size_t)br * HH + (bc4 << 3);
    const int bhiDst = 8192 + (br << 6) + ((bc4 ^ ((br >> 1) & 3)) << 4);

    // ---- B-lo fragments: per-lane direct from L2 (wave-private cols).
    const _Float16* bloSrc[4];
#pragma unroll
    for (int j = 0; j < 4; ++j)
        bloSrc[j] = wpl + (size_t)EE * HH +
                    (size_t)((wn << 6) + (j << 4) + lr) * HH + (lc << 3);

    // ---- fragment LDS read byte offsets (2-way-free swizzled).
    int aRd[2], bRd[4];
#pragma unroll
    for (int i = 0; i < 2; ++i) {
        const int r = (wm << 5) + (i << 4) + lr;
        aRd[i] = (r << 6) + ((lc ^ ((r >> 1) & 3)) << 4);
    }
#pragma unroll
    for (int j = 0; j < 4; ++j) {
        const int r = (wn << 6) + (j << 4) + lr;
        bRd[j] = 8192 + (r << 6) + ((lc ^ ((r >> 1) & 3)) << 4);
    }

    f32x4 accP[2][4] = {};
    f32x4 accS[2][4] = {};
    float4 Aa0, Aa1, Ab0, Ab1;          // x prefetch, 2-deep ping-pong
    uint4 h0, h1;                       // W-hi staging regs
    f16x8 Pa[4], Pb[4];                 // W-lo fragment ping-pong

#define CVT_STORE_A(SMW, X0, X1)                                              \
    if (tid < 256) {                                                          \
        const float fs[8] = {X0.x, X0.y, X0.z, X0.w, X1.x, X1.y, X1.z, X1.w}; \
        f16x8 hi, lo;                                                         \
        _Pragma("unroll") for (int q = 0; q < 8; ++q)                         \
        {                                                                     \
            _Float16 hv = (_Float16)fs[q];                                    \
            hi[q] = hv;                                                       \
            lo[q] = (_Float16)((fs[q] - (float)hv) * 2048.0f);                \
        }                                                                     \
        *(f16x8*)((SMW) + aDst) = hi;                                         \
        *(f16x8*)((SMW) + 4096 + aDst) = lo;                                  \
    }

    // BODY(T): reads buf CUR; writes buf 1-CUR with A(T+1),Bhi(T+1);
    // issues A(T+2)->Y, Bhi(T+1)->h, Blo(T+1)->PLD; MFMAs use PUSE=Blo(T).
#define BODY(T, CUR, X0, X1, Y0, Y1, PUSE, PLD)                               \
    {                                                                         \
        if ((T) < 126 && tid < 256) {                                         \
            const float* ap = aSrc + (size_t)((T) + 2) * 32;                  \
            Y0 = *(const float4*)ap;                                          \
            Y1 = *(const float4*)(ap + 4);                                    \
        }                                                                     \
        if ((T) < 127) {                                                      \
            const _Float16* bp = bhiSrc + (size_t)((T) + 1) * 32;             \
            h0 = *(const uint4*)bp;                                           \
            h1 = *(const uint4*)(bp + (size_t)128 * HH);                      \
            _Pragma("unroll") for (int j = 0; j < 4; ++j)                     \
                PLD[j] = *(const f16x8*)(bloSrc[j] + (size_t)((T) + 1) * 32); \
        }                                                                     \
        const unsigned char* sb = sm[CUR];                                    \
        f16x8 ahh[2], ahl[2], bhh[4];                                         \
        _Pragma("unroll") for (int i = 0; i < 2; ++i)                         \
        {                                                                     \
            ahh[i] = *(const f16x8*)(sb + aRd[i]);                            \
            ahl[i] = *(const f16x8*)(sb + 4096 + aRd[i]);                     \
        }                                                                     \
        _Pragma("unroll") for (int j = 0; j < 4; ++j)                         \
            bhh[j] = *(const f16x8*)(sb + bRd[j]);                            \
        _Pragma("unroll") for (int i = 0; i < 2; ++i)                         \
            _Pragma("unroll") for (int j = 0; j < 4; ++j)                     \
        {                                                                     \
            accP[i][j] = __builtin_amdgcn_mfma_f32_16x16x32_f16(              \
                ahh[i], bhh[j], accP[i][j], 0, 0, 0);                         \
            accS[i][j] = __builtin_amdgcn_mfma_f32_16x16x32_f16(              \
                ahh[i], PUSE[j], accS[i][j], 0, 0, 0);                        \
            accS[i][j] = __builtin_amdgcn_mfma_f32_16x16x32_f16(              \
                ahl[i], bhh[j], accS[i][j], 0, 0, 0);                         \
        }                                                                     \
        if ((T) < 127) {                                                      \
            unsigned char* smw = sm[1 - (CUR)];                               \
            CVT_STORE_A(smw, X0, X1);                                         \
            *(uint4*)(smw + bhiDst) = h0;                                     \
            *(uint4*)(smw + bhiDst + 8192) = h1;                              \
            asm volatile("s_waitcnt lgkmcnt(0)" ::: "memory");                \
            __builtin_amdgcn_s_barrier();                                     \
        }                                                                     \
    }

    // ---- prologue: stage step 0 into buf0; preload A(1), Blo(0).
    if (tid < 256) {
        Aa0 = *(const float4*)aSrc;
        Aa1 = *(const float4*)(aSrc + 4);
    }
    h0 = *(const uint4*)bhiSrc;
    h1 = *(const uint4*)(bhiSrc + (size_t)128 * HH);
#pragma unroll
    for (int j = 0; j < 4; ++j) Pa[j] = *(const f16x8*)bloSrc[j];
    {
        unsigned char* smw = sm[0];
        CVT_STORE_A(smw, Aa0, Aa1);
        *(uint4*)(smw + bhiDst) = h0;
        *(uint4*)(smw + bhiDst + 8192) = h1;
    }
    if (tid < 256) {   // reload Aa with A(1) (write above already consumed it)
        const float* ap = aSrc + 32;
        Aa0 = *(const float4*)ap;
        Aa1 = *(const float4*)(ap + 4);
    }
    asm volatile("s_waitcnt lgkmcnt(0)" ::: "memory");
    __builtin_amdgcn_s_barrier();

    for (int t = 0; t < 128; t += 2) {
        BODY(t,     0, Aa0, Aa1, Ab0, Ab1, Pa, Pb);
        BODY(t + 1, 1, Ab0, Ab1, Aa0, Aa1, Pb, Pa);
    }
#undef BODY
#undef CVT_STORE_A

    // Epilogue. C/D: col = lane&15, row = (lane>>4)*4 + reg [R1-verified].
    float zs = 0.f;
#pragma unroll
    for (int i = 0; i < 2; ++i) {
        const int rb0 = row0 + (wm << 5) + (i << 4) + (lc << 2);
#pragma unroll
        for (int j = 0; j < 4; ++j) {
            const int col = (wn << 6) + (j << 4) + lr;
#pragma unroll
            for (int r = 0; r < 4; ++r) {
                const float raw =
                    accP[i][j][r] + accS[i][j][r] * 4.8828125e-4f;
                zs = fmaf(raw, raw, zs);
                logits[(size_t)(rb0 + r) * EE + col] =
                    1.f / (1.f + expf(-raw));
            }
        }
    }
#pragma unroll
    for (int d = 32; d; d >>= 1) zs += __shfl_xor(zs, d);
    if (lane == 0) zred[wid] = zs;
    __syncthreads();
    if (tid == 0) {
        double zt = 0.0;
#pragma unroll
        for (int q = 0; q < 8; ++q) zt += (double)zred[q];
        zpart[blockIdx.x] = zt;
    }
}

// ---------------------------------------------------------------------------
// Fallback fp32 GEMM (first session's verified kernel) for tiny workspaces.
#define BM 32
#define BK 32
__global__ __launch_bounds__(256) void gemm_fp32_fb_kernel(
    const float* __restrict__ x, const float* __restrict__ w,
    float* __restrict__ logits, double* __restrict__ zacc)
{
    __shared__ float As[BM][BK + 1];
    __shared__ float Bs[EE][BK + 1];
    __shared__ float zred[256];

    const int tid = threadIdx.x;
    const int row0 = blockIdx.x * BM;
    const int ty = tid >> 5;
    const int tx = tid & 31;
    const int lrow = tid >> 3;
    const int lk = (tid & 7) << 2;

    float acc[4][8];
#pragma unroll
    for (int i = 0; i < 4; ++i)
#pragma unroll
        for (int j = 0; j < 8; ++j) acc[i][j] = 0.f;

    for (int k0 = 0; k0 < HH; k0 += BK) {
        float4 xa = *(const float4*)(x + (size_t)(row0 + lrow) * HH + k0 + lk);
        As[lrow][lk + 0] = xa.x;
        As[lrow][lk + 1] = xa.y;
        As[lrow][lk + 2] = xa.z;
        As[lrow][lk + 3] = xa.w;
#pragma unroll
        for (int j = 0; j < 8; ++j) {
            const int e = lrow + (j << 5);
            float4 wb = *(const float4*)(w + (size_t)e * HH + k0 + lk);
            Bs[e][lk + 0] = wb.x;
            Bs[e][lk + 1] = wb.y;
            Bs[e][lk + 2] = wb.z;
            Bs[e][lk + 3] = wb.w;
        }
        __syncthreads();
#pragma unroll 8
        for (int kk = 0; kk < BK; ++kk) {
            float a[4], bb[8];
#pragma unroll
            for (int i = 0; i < 4; ++i) a[i] = As[ty * 4 + i][kk];
#pragma unroll
            for (int j = 0; j < 8; ++j) bb[j] = Bs[tx + (j << 5)][kk];
#pragma unroll
            for (int i = 0; i < 4; ++i)
#pragma unroll
                for (int j = 0; j < 8; ++j)
                    acc[i][j] = fmaf(a[i], bb[j], acc[i][j]);
        }
        __syncthreads();
    }

    float zs = 0.f;
#pragma unroll
    for (int i = 0; i < 4; ++i) {
        const int r = row0 + ty * 4 + i;
#pragma unroll
        for (int j = 0; j < 8; ++j) {
            const float v = acc[i][j];
            zs = fmaf(v, v, zs);
            logits[(size_t)r * EE + tx + (j << 5)] = 1.f / (1.f + expf(-v));
        }
    }
    zred[tid] = zs;
    __syncthreads();
    for (int s = 128; s > 0; s >>= 1) {
        if (tid < s) zred[tid] += zred[tid + s];
        __syncthreads();
    }
    if (tid == 0) atom_add_double(zacc, (double)zred[0]);
}

// ---------------------------------------------------------------------------
// Router: one wave (64 lanes) per token; lane l owns experts 4l..4l+3.
// Matches jax.lax.top_k stability: ties broken toward the LOWER index.
__global__ __launch_bounds__(256) void router_kernel(
    const float* __restrict__ logits, const float* __restrict__ bias,
    float* __restrict__ wout, float* __restrict__ iout)
{
    const int lane = threadIdx.x & 63;
    const int wv = threadIdx.x >> 6;
    const int t = blockIdx.x * 4 + wv;

    const float* lrow = logits + (size_t)t * EE + lane * 4;
    float lg[4];
#pragma unroll
    for (int q = 0; q < 4; ++q) lg[q] = lrow[q];
    const float4 b4 = *(const float4*)(bias + lane * 4);
    const float bb[4] = {b4.x, b4.y, b4.z, b4.w};

    float sel[4];
#pragma unroll
    for (int q = 0; q < 4; ++q) sel[q] = lg[q] + bb[q];

    float m1 = sel[0], m2 = -INFINITY;
#pragma unroll
    for (int q = 1; q < 4; ++q) {
        if (sel[q] > m1) { m2 = m1; m1 = sel[q]; }
        else             { m2 = fmaxf(m2, sel[q]); }
    }
#pragma unroll
    for (int d = 1; d < 8; d <<= 1) {
        const float o1 = __shfl_xor(m1, d);
        const float o2 = __shfl_xor(m2, d);
        const float nm1 = fmaxf(m1, o1);
        const float nm2 = fmaxf(fminf(m1, o1), fmaxf(m2, o2));
        m1 = nm1; m2 = nm2;
    }
    const float gs = m1 + m2;
    const int g = lane >> 3;

    int rank = 0;
#pragma unroll
    for (int gp = 0; gp < 8; ++gp) {
        const float og = __shfl(gs, gp << 3);
        rank += (og > gs) || (og == gs && gp < g);
    }
    const bool keep = rank < 4;

    float ms[4];
#pragma unroll
    for (int q = 0; q < 4; ++q)
        ms[q] = keep ? sel[q] : -3.402823466e38f;

    float wvals[8];
    int widx[8];
#pragma unroll
    for (int it = 0; it < 8; ++it) {
        float bv = ms[0];
        int bq = 0;
#pragma unroll
        for (int q = 1; q < 4; ++q)
            if (ms[q] > bv) { bv = ms[q]; bq = q; }
        int bi = (lane << 2) + bq;
        float bl = lg[bq];
#pragma unroll
        for (int d = 1; d < 64; d <<= 1) {
            const float ov = __shfl_xor(bv, d);
            const int oi = __shfl_xor(bi, d);
            const float ol = __shfl_xor(bl, d);
            if (ov > bv || (ov == bv && oi < bi)) { bv = ov; bi = oi; bl = ol; }
        }
        wvals[it] = bl;
        widx[it] = bi;
        if ((bi >> 2) == lane) ms[bi & 3] = -INFINITY;
    }

    float s = 0.f;
#pragma unroll
    for (int it = 0; it < 8; ++it) s += wvals[it];
    s = fmaxf(s, 1e-9f);

    if (lane == 0) {
#pragma unroll
        for (int it = 0; it < 8; ++it) {
            wout[(size_t)t * 8 + it] = wvals[it] / s;
            iout[(size_t)t * 8 + it] = (float)widx[it];
        }
    }
}

// ---------------------------------------------------------------------------
extern "C" void kernel_launch(void* const* d_in, const int* in_sizes, int n_in,
                              void* d_out, int out_size, void* d_ws,
                              size_t ws_size, hipStream_t stream) {
    const float* x = (const float*)d_in[0];     // (TT, HH)
    const float* w = (const float*)d_in[1];     // (EE, HH)
    const float* bias = (const float*)d_in[2];  // (EE)

    float* out = (float*)d_out;
    float* wout = out;
    float* iout = out + (size_t)TT * 8;
    float* zout = out + (size_t)TT * 16;
    float* logits = zout + 1;
    double* zacc = (double*)d_ws;

    // ws layout: [0,8)=zacc (fallback), [1024,3072)=zpart[256], [4096,..)=wpl
    const size_t need = 4096 + (size_t)2 * EE * HH * sizeof(_Float16);
    if (ws_size >= need) {
        double* zpart = (double*)((char*)d_ws + 1024);
        _Float16* wpl = (_Float16*)((char*)d_ws + 4096);
        prep_w_kernel<<<EE, 256, 0, stream>>>(w, wpl);
        gemm_mfma_kernel<<<TT / 64, 512, 0, stream>>>(x, wpl, logits, zpart);
        finalize_zpart_kernel<<<1, 256, 0, stream>>>(zpart, zout);
    } else {
        zero_ws_kernel<<<1, 64, 0, stream>>>(zacc);
        gemm_fp32_fb_kernel<<<TT / BM, 256, 0, stream>>>(x, w, logits, zacc);
        finalize_z_kernel<<<1, 64, 0, stream>>>(zacc, zout);
    }
    router_kernel<<<TT / 4, 256, 0, stream>>>(logits, bias, wout, iout);
}

// Round 5
// 547.800 us; speedup vs baseline: 2.6971x; 1.0069x over previous
//
#include <hip/hip_runtime.h>
#include <math.h>

// Problem constants (fixed by setup_inputs).
#define TT 16384
#define HH 4096
#define EE 256

typedef _Float16 f16x8 __attribute__((ext_vector_type(8)));
typedef float f32x4 __attribute__((ext_vector_type(4)));

// ---------------------------------------------------------------------------
// CAS-based double atomic add (fallback path only).
__device__ inline void atom_add_double(double* addr, double val) {
    unsigned long long* p = (unsigned long long*)addr;
    unsigned long long old = *p, assumed;
    do {
        assumed = old;
        double nv = __longlong_as_double(assumed) + val;
        old = atomicCAS(p, assumed, __double_as_longlong(nv));
    } while (old != assumed);
}

__global__ __launch_bounds__(64) void zero_ws_kernel(double* z) {
    if (threadIdx.x == 0) *z = 0.0;
}

__global__ __launch_bounds__(64) void finalize_z_kernel(const double* zacc,
                                                        float* zout) {
    if (threadIdx.x == 0)
        *zout = (float)(*zacc / (double)((size_t)TT * (size_t)EE));
}

// Sums 512 per-block partials.
__global__ __launch_bounds__(256) void finalize_zpart_kernel(
    const double* __restrict__ zpart, float* __restrict__ zout) {
    __shared__ double zr[256];
    zr[threadIdx.x] = zpart[threadIdx.x] + zpart[threadIdx.x + 256];
    __syncthreads();
    for (int s = 128; s > 0; s >>= 1) {
        if (threadIdx.x < s) zr[threadIdx.x] += zr[threadIdx.x + s];
        __syncthreads();
    }
    if (threadIdx.x == 0)
        *zout = (float)(zr[0] / ((double)TT * (double)EE));
}

// ---------------------------------------------------------------------------
// Prep: W (E x H fp32) -> f16 planes: hi = f16(w), lo = f16((w - hi)*2048).
__global__ __launch_bounds__(256) void prep_w_kernel(
    const float* __restrict__ w, _Float16* __restrict__ wpl)
{
    const int e = blockIdx.x;
    for (int c = threadIdx.x; c < 512; c += 256) {
        const int k = c << 3;
        const float* src = w + (size_t)e * HH + k;
        const float4 f0 = *(const float4*)src;
        const float4 f1 = *(const float4*)(src + 4);
        const float fs[8] = {f0.x, f0.y, f0.z, f0.w, f1.x, f1.y, f1.z, f1.w};
        f16x8 hi, lo;
#pragma unroll
        for (int q = 0; q < 8; ++q) {
            _Float16 h = (_Float16)fs[q];
            hi[q] = h;
            lo[q] = (_Float16)((fs[q] - (float)h) * 2048.0f);
        }
        *(f16x8*)(wpl + (size_t)e * HH + k) = hi;
        *(f16x8*)(wpl + (size_t)EE * HH + (size_t)e * HH + k) = lo;
    }
}

// ---------------------------------------------------------------------------
// MFMA GEMM v4: raw = x @ W^T via fp16 two-term split:
//   raw = sum(xh*wh) + [sum(xh*wl') + sum(xl'*wh)] / 2048      (ll dropped)
// Tile BM=64 x BN=128, BK=32. 512 threads = 8 waves (2M x 4N), wave-tile
// 32x32 (M_rep=2, N_rep=2). Grid 512 = 2 blocks/CU (16 waves/CU): the two
// co-resident blocks have independent barriers -> one block's MFMA fills the
// other's stall window (R4 was 1 block/CU, occupancy 23%, stall-bound).
// XCD-pair swizzle: bids b and b+8 (same XCD under RR dispatch) get the two
// column-halves of the SAME row band -> x slab shared through that XCD's L2.
// Reg-staged + RAW barriers (lgkmcnt(0)+s_barrier, no vmcnt drain): global
// loads pipeline across K-steps (x 2-deep, W-hi/W-lo 1-deep). W-lo plane
// skips LDS: wave-private fragments per-lane from L2, ping-ponged registers.
// LDS per buffer 16384 B: A-hi @0 (4K), A-lo @4096 (4K), B-hi @8192 (8K).
// XOR slot swizzle (c ^ (r>>1)&3) on all staged tiles -> 2-way (free) LDS.
__global__ __launch_bounds__(512, 4) void gemm_mfma_kernel(
    const float* __restrict__ x,        // (TT, HH) fp32
    const _Float16* __restrict__ wpl,   // [2][EE][HH] f16 planes
    float* __restrict__ logits,         // (TT, EE)
    double* __restrict__ zpart)         // (512) per-block z partials
{
    __shared__ __align__(16) unsigned char sm[2][16384];
    __shared__ float zred[8];

    const int tid  = threadIdx.x;
    const int lane = tid & 63;
    const int wid  = tid >> 6;          // 0..7
    const int wm   = wid >> 2;          // 0..1 (row half of 64)
    const int wn   = wid & 3;           // 0..3 (col quarter of 128)
    const int lr   = lane & 15;
    const int lc   = lane >> 4;

    // XCD-pair swizzle: xcd = bid&7; idx = bid>>3; pair (idx>>1) shares rows.
    const int bid  = blockIdx.x;
    const int rb   = ((bid & 7) << 5) + (bid >> 4);   // 0..255 row band
    const int cb   = (bid >> 3) & 1;                  // column half
    const int row0 = rb << 6;
    const int col0 = cb << 7;

    // ---- A staging (threads 0..255): 32 B of x (8 fp32) per thread/step.
    const int arow = tid >> 2, ac32 = tid & 3;
    const float* aSrc = x + (size_t)(row0 + arow) * HH + (ac32 << 3);
    const int aDst = (arow << 6) + ((ac32 ^ ((arow >> 1) & 3)) << 4);

    // ---- B-hi staging: one 16 B job per thread (rows col0..col0+127).
    const int br = tid >> 2, bc4 = tid & 3;
    const _Float16* bhiSrc = wpl + (size_t)(col0 + br) * HH + (bc4 << 3);
    const int bhiDst = 8192 + (br << 6) + ((bc4 ^ ((br >> 1) & 3)) << 4);

    // ---- B-lo fragments: per-lane direct from L2 (wave-private cols).
    const _Float16* bloSrc[2];
#pragma unroll
    for (int j = 0; j < 2; ++j)
        bloSrc[j] = wpl + (size_t)EE * HH +
                    (size_t)(col0 + (wn << 5) + (j << 4) + lr) * HH + (lc << 3);

    // ---- fragment LDS read byte offsets (2-way-free swizzled).
    int aRd[2], bRd[2];
#pragma unroll
    for (int i = 0; i < 2; ++i) {
        const int r = (wm << 5) + (i << 4) + lr;
        aRd[i] = (r << 6) + ((lc ^ ((r >> 1) & 3)) << 4);
    }
#pragma unroll
    for (int j = 0; j < 2; ++j) {
        const int r = (wn << 5) + (j << 4) + lr;
        bRd[j] = 8192 + (r << 6) + ((lc ^ ((r >> 1) & 3)) << 4);
    }

    f32x4 accP[2][2] = {};
    f32x4 accS[2][2] = {};
    float4 Aa0, Aa1, Ab0, Ab1;          // x prefetch, 2-deep ping-pong
    uint4 h0;                           // W-hi staging reg
    f16x8 Pa[2], Pb[2];                 // W-lo fragment ping-pong

#define CVT_STORE_A(SMW, X0, X1)                                              \
    if (tid < 256) {                                                          \
        const float fs[8] = {X0.x, X0.y, X0.z, X0.w, X1.x, X1.y, X1.z, X1.w}; \
        f16x8 hi, lo;                                                         \
        _Pragma("unroll") for (int q = 0; q < 8; ++q)                         \
        {                                                                     \
            _Float16 hv = (_Float16)fs[q];                                    \
            hi[q] = hv;                                                       \
            lo[q] = (_Float16)((fs[q] - (float)hv) * 2048.0f);                \
        }                                                                     \
        *(f16x8*)((SMW) + aDst) = hi;                                         \
        *(f16x8*)((SMW) + 4096 + aDst) = lo;                                  \
    }

    // BODY(T): reads buf CUR; writes buf 1-CUR with A(T+1),Bhi(T+1);
    // issues A(T+2)->Y, Bhi(T+1)->h0, Blo(T+1)->PLD; MFMAs use PUSE=Blo(T).
#define BODY(T, CUR, X0, X1, Y0, Y1, PUSE, PLD)                               \
    {                                                                         \
        if ((T) < 126 && tid < 256) {                                         \
            const float* ap = aSrc + (size_t)((T) + 2) * 32;                  \
            Y0 = *(const float4*)ap;                                          \
            Y1 = *(const float4*)(ap + 4);                                    \
        }                                                                     \
        if ((T) < 127) {                                                      \
            h0 = *(const uint4*)(bhiSrc + (size_t)((T) + 1) * 32);            \
            _Pragma("unroll") for (int j = 0; j < 2; ++j)                     \
                PLD[j] = *(const f16x8*)(bloSrc[j] + (size_t)((T) + 1) * 32); \
        }                                                                     \
        const unsigned char* sb = sm[CUR];                                    \
        f16x8 ahh[2], ahl[2], bhh[2];                                         \
        _Pragma("unroll") for (int i = 0; i < 2; ++i)                         \
        {                                                                     \
            ahh[i] = *(const f16x8*)(sb + aRd[i]);                            \
            ahl[i] = *(const f16x8*)(sb + 4096 + aRd[i]);                     \
        }                                                                     \
        _Pragma("unroll") for (int j = 0; j < 2; ++j)                         \
            bhh[j] = *(const f16x8*)(sb + bRd[j]);                            \
        _Pragma("unroll") for (int i = 0; i < 2; ++i)                         \
            _Pragma("unroll") for (int j = 0; j < 2; ++j)                     \
        {                                                                     \
            accP[i][j] = __builtin_amdgcn_mfma_f32_16x16x32_f16(              \
                ahh[i], bhh[j], accP[i][j], 0, 0, 0);                         \
            accS[i][j] = __builtin_amdgcn_mfma_f32_16x16x32_f16(              \
                ahh[i], PUSE[j], accS[i][j], 0, 0, 0);                        \
            accS[i][j] = __builtin_amdgcn_mfma_f32_16x16x32_f16(              \
                ahl[i], bhh[j], accS[i][j], 0, 0, 0);                         \
        }                                                                     \
        if ((T) < 127) {                                                      \
            unsigned char* smw = sm[1 - (CUR)];                               \
            CVT_STORE_A(smw, X0, X1);                                         \
            *(uint4*)(smw + bhiDst) = h0;                                     \
            asm volatile("s_waitcnt lgkmcnt(0)" ::: "memory");                \
            __builtin_amdgcn_s_barrier();                                     \
        }                                                                     \
    }

    // ---- prologue: stage step 0 into buf0; preload A(1), Blo(0).
    if (tid < 256) {
        Aa0 = *(const float4*)aSrc;
        Aa1 = *(const float4*)(aSrc + 4);
    }
    h0 = *(const uint4*)bhiSrc;
#pragma unroll
    for (int j = 0; j < 2; ++j) Pa[j] = *(const f16x8*)bloSrc[j];
    {
        unsigned char* smw = sm[0];
        CVT_STORE_A(smw, Aa0, Aa1);
        *(uint4*)(smw + bhiDst) = h0;
    }
    if (tid < 256) {   // reload Aa with A(1) (write above already consumed it)
        const float* ap = aSrc + 32;
        Aa0 = *(const float4*)ap;
        Aa1 = *(const float4*)(ap + 4);
    }
    asm volatile("s_waitcnt lgkmcnt(0)" ::: "memory");
    __builtin_amdgcn_s_barrier();

    for (int t = 0; t < 128; t += 2) {
        BODY(t,     0, Aa0, Aa1, Ab0, Ab1, Pa, Pb);
        BODY(t + 1, 1, Ab0, Ab1, Aa0, Aa1, Pb, Pa);
    }
#undef BODY
#undef CVT_STORE_A

    // Epilogue. C/D: col = lane&15, row = (lane>>4)*4 + reg [R1/R4-verified].
    float zs = 0.f;
#pragma unroll
    for (int i = 0; i < 2; ++i) {
        const int rb0 = row0 + (wm << 5) + (i << 4) + (lc << 2);
#pragma unroll
        for (int j = 0; j < 2; ++j) {
            const int col = col0 + (wn << 5) + (j << 4) + lr;
#pragma unroll
            for (int r = 0; r < 4; ++r) {
                const float raw =
                    accP[i][j][r] + accS[i][j][r] * 4.8828125e-4f;
                zs = fmaf(raw, raw, zs);
                logits[(size_t)(rb0 + r) * EE + col] =
                    1.f / (1.f + expf(-raw));
            }
        }
    }
#pragma unroll
    for (int d = 32; d; d >>= 1) zs += __shfl_xor(zs, d);
    if (lane == 0) zred[wid] = zs;
    __syncthreads();
    if (tid == 0) {
        double zt = 0.0;
#pragma unroll
        for (int q = 0; q < 8; ++q) zt += (double)zred[q];
        zpart[bid] = zt;
    }
}

// ---------------------------------------------------------------------------
// Fallback fp32 GEMM (first session's verified kernel) for tiny workspaces.
#define BM 32
#define BK 32
__global__ __launch_bounds__(256) void gemm_fp32_fb_kernel(
    const float* __restrict__ x, const float* __restrict__ w,
    float* __restrict__ logits, double* __restrict__ zacc)
{
    __shared__ float As[BM][BK + 1];
    __shared__ float Bs[EE][BK + 1];
    __shared__ float zred[256];

    const int tid = threadIdx.x;
    const int row0 = blockIdx.x * BM;
    const int ty = tid >> 5;
    const int tx = tid & 31;
    const int lrow = tid >> 3;
    const int lk = (tid & 7) << 2;

    float acc[4][8];
#pragma unroll
    for (int i = 0; i < 4; ++i)
#pragma unroll
        for (int j = 0; j < 8; ++j) acc[i][j] = 0.f;

    for (int k0 = 0; k0 < HH; k0 += BK) {
        float4 xa = *(const float4*)(x + (size_t)(row0 + lrow) * HH + k0 + lk);
        As[lrow][lk + 0] = xa.x;
        As[lrow][lk + 1] = xa.y;
        As[lrow][lk + 2] = xa.z;
        As[lrow][lk + 3] = xa.w;
#pragma unroll
        for (int j = 0; j < 8; ++j) {
            const int e = lrow + (j << 5);
            float4 wb = *(const float4*)(w + (size_t)e * HH + k0 + lk);
            Bs[e][lk + 0] = wb.x;
            Bs[e][lk + 1] = wb.y;
            Bs[e][lk + 2] = wb.z;
            Bs[e][lk + 3] = wb.w;
        }
        __syncthreads();
#pragma unroll 8
        for (int kk = 0; kk < BK; ++kk) {
            float a[4], bb[8];
#pragma unroll
            for (int i = 0; i < 4; ++i) a[i] = As[ty * 4 + i][kk];
#pragma unroll
            for (int j = 0; j < 8; ++j) bb[j] = Bs[tx + (j << 5)][kk];
#pragma unroll
            for (int i = 0; i < 4; ++i)
#pragma unroll
                for (int j = 0; j < 8; ++j)
                    acc[i][j] = fmaf(a[i], bb[j], acc[i][j]);
        }
        __syncthreads();
    }

    float zs = 0.f;
#pragma unroll
    for (int i = 0; i < 4; ++i) {
        const int r = row0 + ty * 4 + i;
#pragma unroll
        for (int j = 0; j < 8; ++j) {
            const float v = acc[i][j];
            zs = fmaf(v, v, zs);
            logits[(size_t)r * EE + tx + (j << 5)] = 1.f / (1.f + expf(-v));
        }
    }
    zred[tid] = zs;
    __syncthreads();
    for (int s = 128; s > 0; s >>= 1) {
        if (tid < s) zred[tid] += zred[tid + s];
        __syncthreads();
    }
    if (tid == 0) atom_add_double(zacc, (double)zred[0]);
}

// ---------------------------------------------------------------------------
// Router: one wave (64 lanes) per token; lane l owns experts 4l..4l+3.
// Matches jax.lax.top_k stability: ties broken toward the LOWER index.
__global__ __launch_bounds__(256) void router_kernel(
    const float* __restrict__ logits, const float* __restrict__ bias,
    float* __restrict__ wout, float* __restrict__ iout)
{
    const int lane = threadIdx.x & 63;
    const int wv = threadIdx.x >> 6;
    const int t = blockIdx.x * 4 + wv;

    const float* lrow = logits + (size_t)t * EE + lane * 4;
    float lg[4];
#pragma unroll
    for (int q = 0; q < 4; ++q) lg[q] = lrow[q];
    const float4 b4 = *(const float4*)(bias + lane * 4);
    const float bb[4] = {b4.x, b4.y, b4.z, b4.w};

    float sel[4];
#pragma unroll
    for (int q = 0; q < 4; ++q) sel[q] = lg[q] + bb[q];

    float m1 = sel[0], m2 = -INFINITY;
#pragma unroll
    for (int q = 1; q < 4; ++q) {
        if (sel[q] > m1) { m2 = m1; m1 = sel[q]; }
        else             { m2 = fmaxf(m2, sel[q]); }
    }
#pragma unroll
    for (int d = 1; d < 8; d <<= 1) {
        const float o1 = __shfl_xor(m1, d);
        const float o2 = __shfl_xor(m2, d);
        const float nm1 = fmaxf(m1, o1);
        const float nm2 = fmaxf(fminf(m1, o1), fmaxf(m2, o2));
        m1 = nm1; m2 = nm2;
    }
    const float gs = m1 + m2;
    const int g = lane >> 3;

    int rank = 0;
#pragma unroll
    for (int gp = 0; gp < 8; ++gp) {
        const float og = __shfl(gs, gp << 3);
        rank += (og > gs) || (og == gs && gp < g);
    }
    const bool keep = rank < 4;

    float ms[4];
#pragma unroll
    for (int q = 0; q < 4; ++q)
        ms[q] = keep ? sel[q] : -3.402823466e38f;

    float wvals[8];
    int widx[8];
#pragma unroll
    for (int it = 0; it < 8; ++it) {
        float bv = ms[0];
        int bq = 0;
#pragma unroll
        for (int q = 1; q < 4; ++q)
            if (ms[q] > bv) { bv = ms[q]; bq = q; }
        int bi = (lane << 2) + bq;
        float bl = lg[bq];
#pragma unroll
        for (int d = 1; d < 64; d <<= 1) {
            const float ov = __shfl_xor(bv, d);
            const int oi = __shfl_xor(bi, d);
            const float ol = __shfl_xor(bl, d);
            if (ov > bv || (ov == bv && oi < bi)) { bv = ov; bi = oi; bl = ol; }
        }
        wvals[it] = bl;
        widx[it] = bi;
        if ((bi >> 2) == lane) ms[bi & 3] = -INFINITY;
    }

    float s = 0.f;
#pragma unroll
    for (int it = 0; it < 8; ++it) s += wvals[it];
    s = fmaxf(s, 1e-9f);

    if (lane == 0) {
#pragma unroll
        for (int it = 0; it < 8; ++it) {
            wout[(size_t)t * 8 + it] = wvals[it] / s;
            iout[(size_t)t * 8 + it] = (float)widx[it];
        }
    }
}

// ---------------------------------------------------------------------------
extern "C" void kernel_launch(void* const* d_in, const int* in_sizes, int n_in,
                              void* d_out, int out_size, void* d_ws,
                              size_t ws_size, hipStream_t stream) {
    const float* x = (const float*)d_in[0];     // (TT, HH)
    const float* w = (const float*)d_in[1];     // (EE, HH)
    const float* bias = (const float*)d_in[2];  // (EE)

    float* out = (float*)d_out;
    float* wout = out;
    float* iout = out + (size_t)TT * 8;
    float* zout = out + (size_t)TT * 16;
    float* logits = zout + 1;
    double* zacc = (double*)d_ws;

    // ws layout: [0,8)=zacc (fb), [1024,5120)=zpart[512], [8192,..)=wpl
    const size_t need = 8192 + (size_t)2 * EE * HH * sizeof(_Float16);
    if (ws_size >= need) {
        double* zpart = (double*)((char*)d_ws + 1024);
        _Float16* wpl = (_Float16*)((char*)d_ws + 8192);
        prep_w_kernel<<<EE, 256, 0, stream>>>(w, wpl);
        gemm_mfma_kernel<<<(TT / 64) * 2, 512, 0, stream>>>(x, wpl, logits,
                                                            zpart);
        finalize_zpart_kernel<<<1, 256, 0, stream>>>(zpart, zout);
    } else {
        zero_ws_kernel<<<1, 64, 0, stream>>>(zacc);
        gemm_fp32_fb_kernel<<<TT / BM, 256, 0, stream>>>(x, w, logits, zacc);
        finalize_z_kernel<<<1, 64, 0, stream>>>(zacc, zout);
    }
    router_kernel<<<TT / 4, 256, 0, stream>>>(logits, bias, wout, iout);
}